// Round 7
// baseline (94.315 us; speedup 1.0000x reference)
//
#include <hip/hip_runtime.h>
#include <math.h>

#define L        512
#define BLK      256
#define WPB      4          // waves (graphs) per block
#define KTOP     32
#define NEGV     (-1e30f)

#define LOG2E    1.4426950408889634f
#define LOG2E10  14.426950408889634f   // (1/T=10) * log2(e)
#define LN2      0.6931471805599453f
#define M_L2E    0.7213475204444817f   // MARGIN(0.5) * log2(e)

#if __has_builtin(__builtin_amdgcn_exp2f)
#define EXP2F(x) __builtin_amdgcn_exp2f(x)
#else
#define EXP2F(x) exp2f(x)
#endif
#if __has_builtin(__builtin_amdgcn_logf)
#define LOG2F(x) __builtin_amdgcn_logf(x)
#else
#define LOG2F(x) __log2f(x)
#endif

// softplus(x)/ln2 with x2 = x*log2e:  max(x2,0) + log2(1 + 2^(-|x2|))
__device__ __forceinline__ float softplus_l2(float x2) {
    return fmaxf(x2, 0.0f) + LOG2F(1.0f + EXP2F(fminf(x2, -x2)));
}

// # of set bits in m strictly below this lane
__device__ __forceinline__ unsigned lanes_below(unsigned long long m) {
    return __builtin_amdgcn_mbcnt_hi((unsigned)(m >> 32),
           __builtin_amdgcn_mbcnt_lo((unsigned)(m & 0xffffffffull), 0u));
}

__global__ __launch_bounds__(BLK) void graph_loss_kernel(
    const float* __restrict__ logits,
    const float* __restrict__ targets,
    int G,
    int* __restrict__ counter,          // zeroed before launch
    float4* __restrict__ partials,      // [gridDim.x]
    float* __restrict__ out)
{
    __shared__ float pos_s[WPB][L];      // positives, pre-scaled by log2e
    __shared__ float hard_s[WPB][KTOP];  // hard negs in c2 units
    __shared__ float wres[WPB][4];
    __shared__ int   lastFlag;

    const int tid  = threadIdx.x;
    const int lane = tid & 63;
    const int w    = tid >> 6;
    const int g    = blockIdx.x * WPB + w;
    const bool valid = (g < G);          // wave-uniform

    float lw = 0.0f, contrib = 0.0f, hp = 0.0f, act = 0.0f;

    if (valid) {
        // Each lane owns elements [lane*8, lane*8+8): two float4 loads each.
        const float4* lg4 = (const float4*)(logits  + (size_t)g * L);
        const float4* tg4 = (const float4*)(targets + (size_t)g * L);
        const float4 la = lg4[lane * 2], lb = lg4[lane * 2 + 1];
        const float4 ta = tg4[lane * 2], tb = tg4[lane * 2 + 1];
        float v[8]  = {la.x, la.y, la.z, la.w, lb.x, lb.y, lb.z, lb.w};
        float tv[8] = {ta.x, ta.y, ta.z, ta.w, tb.x, tb.y, tb.z, tb.w};
        bool  p[8];
        unsigned nu[8];  // order-preserving uint key of negatives; 0 for pos

#pragma unroll
        for (int e = 0; e < 8; e++) {
            p[e] = tv[e] > 0.5f;
            const unsigned i = __float_as_uint(v[e]);
            const unsigned msk = (unsigned)((int)i >> 31) | 0x80000000u;
            nu[e] = p[e] ? 0u : (i ^ msk);
        }

        // ---- compact positives (pre-scaled by log2e) into LDS; get P ----
        int pbase = 0;
#pragma unroll
        for (int e = 0; e < 8; e++) {
            const unsigned long long m = __ballot((int)p[e]);
            if (p[e]) pos_s[w][pbase + lanes_below(m)] = v[e] * LOG2E;
            pbase += __popcll(m);
        }
        const int P = pbase;

        // ---- listwise LSEs in log2 domain; shared max (s_mx cancels) ----
        float u[8];
        float s_mx = NEGV;
#pragma unroll
        for (int e = 0; e < 8; e++) {
            u[e] = v[e] * LOG2E10;
            s_mx = fmaxf(s_mx, u[e]);
        }
#pragma unroll
        for (int off = 32; off; off >>= 1)
            s_mx = fmaxf(s_mx, __shfl_xor(s_mx, off, 64));

        float se_all = 0.0f, se_pos = 0.0f;
#pragma unroll
        for (int e = 0; e < 8; e++) {
            const float ep = EXP2F(u[e] - s_mx);
            se_all += ep;
            se_pos += p[e] ? ep : 0.0f;
        }
#pragma unroll
        for (int off = 32; off; off >>= 1) {
            se_all += __shfl_xor(se_all, off, 64);
            se_pos += __shfl_xor(se_pos, off, 64);
        }

        if (P > 0) {
            hp = 1.0f;
            lw = LN2 * (LOG2F(se_all) - LOG2F(se_pos));
        }
        const int neg_cnt = L - P;
        const int K = neg_cnt < KTOP ? neg_cnt : KTOP;

        if (P > 0 && K > 0) {
            // ---- radix-select threshold key of K-th largest negative ----
            unsigned prefix = 0u;
            int exact = 0;
            for (int b = 31; b >= 0; --b) {
                const unsigned cand = prefix | (1u << b);
                int cnt = 0;
#pragma unroll
                for (int e = 0; e < 8; e++)
                    cnt += __popcll(__ballot(nu[e] >= cand));
                if (cnt >= K) {
                    prefix = cand;
                    if (cnt == K) { exact = 1; break; }
                }
            }
            const unsigned lo = prefix - (unsigned)exact;  // select keys > lo
            const unsigned ti = prefix ^ ((prefix & 0x80000000u) ? 0x80000000u
                                                                 : 0xFFFFFFFFu);
            const float tval = __uint_as_float(ti);
            const float tc2  = fmaf(tval, LOG2E, M_L2E);   // tie value, c2 units

            // ---- compact hard negatives in c2 units (0.5 + h)*log2e ----
            int hbase = 0;
#pragma unroll
            for (int e = 0; e < 8; e++) {
                const bool gt = nu[e] > lo;
                const unsigned long long m = __ballot((int)gt);
                if (gt) hard_s[w][hbase + lanes_below(m)] =
                            fmaf(v[e], LOG2E, M_L2E);
                hbase += __popcll(m);
            }
            const int c_gt = hbase;  // ties fill the remaining K - c_gt slots

            float psum = 0.0f;
            if (K == KTOP) {
                // fast path: lane n<32 holds hard value n in a register;
                // lanes c_gt..31 hold the tie value (exact top-32 multiset).
                const float hc = (lane < c_gt) ? hard_s[w][lane & (KTOP - 1)]
                                               : tc2;
                for (int base = 0; base < P; base += 64) {
                    const float qs = pos_s[w][base + lane]; // garbage if >=P,
                    float a0 = 0.0f, a1 = 0.0f, a2 = 0.0f, a3 = 0.0f;
#pragma unroll
                    for (int n = 0; n < KTOP; n += 4) {     // masked out below
                        a0 += softplus_l2(__shfl(hc, n + 0, 64) - qs);
                        a1 += softplus_l2(__shfl(hc, n + 1, 64) - qs);
                        a2 += softplus_l2(__shfl(hc, n + 2, 64) - qs);
                        a3 += softplus_l2(__shfl(hc, n + 3, 64) - qs);
                    }
                    const float s = (a0 + a1) + (a2 + a3);
                    psum += (base + lane < P) ? s : 0.0f;
                }
            } else {
                // general path (K < 32): LDS loop + weighted tie term
                for (int n = 0; n < c_gt; n++) {
                    const float c2 = hard_s[w][n];
                    for (int pp = lane; pp < P; pp += 64)
                        psum += softplus_l2(c2 - pos_s[w][pp]);
                }
                if (K > c_gt) {
                    float t = 0.0f;
                    for (int pp = lane; pp < P; pp += 64)
                        t += softplus_l2(tc2 - pos_s[w][pp]);
                    psum += (float)(K - c_gt) * t;
                }
            }
#pragma unroll
            for (int off = 32; off; off >>= 1)
                psum += __shfl_xor(psum, off, 64);
            contrib = LN2 * psum / fmaxf((float)P * (float)K, 1.0f);
            act = 1.0f;
        }
    }

    if (lane == 0) {
        wres[w][0] = lw;
        wres[w][1] = hp;
        wres[w][2] = contrib;
        wres[w][3] = act;
    }
    __syncthreads();

    // ---- single-writer block partial + last-block-done reduction ----
    if (tid == 0) {
        partials[blockIdx.x] = make_float4(
            wres[0][0] + wres[1][0] + wres[2][0] + wres[3][0],
            wres[0][1] + wres[1][1] + wres[2][1] + wres[3][1],
            wres[0][2] + wres[1][2] + wres[2][2] + wres[3][2],
            wres[0][3] + wres[1][3] + wres[2][3] + wres[3][3]);
        __threadfence();  // make partial visible device-wide before the atomic
        const int old = atomicAdd(counter, 1);
        lastFlag = (old == (int)gridDim.x - 1);
    }
    __syncthreads();

    if (lastFlag) {
        __threadfence();  // acquire: other blocks' partials now visible
        const int nblocks = gridDim.x;
        float s0 = 0, s1 = 0, s2 = 0, s3 = 0;
        for (int i = tid; i < nblocks; i += BLK) {
            const float4 p = partials[i];
            s0 += p.x; s1 += p.y; s2 += p.z; s3 += p.w;
        }
#pragma unroll
        for (int off = 32; off; off >>= 1) {
            s0 += __shfl_xor(s0, off, 64);
            s1 += __shfl_xor(s1, off, 64);
            s2 += __shfl_xor(s2, off, 64);
            s3 += __shfl_xor(s3, off, 64);
        }
        __shared__ float red[4][4];
        if (lane == 0) {
            red[w][0] = s0; red[w][1] = s1; red[w][2] = s2; red[w][3] = s3;
        }
        __syncthreads();
        if (tid == 0) {
            const float a0 = red[0][0]+red[1][0]+red[2][0]+red[3][0];
            const float a1 = red[0][1]+red[1][1]+red[2][1]+red[3][1];
            const float a2 = red[0][2]+red[1][2]+red[2][2]+red[3][2];
            const float a3 = red[0][3]+red[1][3]+red[2][3]+red[3][3];
            const float listwise = a0 / fmaxf(a1, 1.0f);
            const float pairwise = a2 / fmaxf(a3, 1.0f);
            out[0] = 1.0f * listwise + 0.5f * pairwise;
        }
    }
}

extern "C" void kernel_launch(void* const* d_in, const int* in_sizes, int n_in,
                              void* d_out, int out_size, void* d_ws, size_t ws_size,
                              hipStream_t stream) {
    const float* logits  = (const float*)d_in[0];
    const float* targets = (const float*)d_in[1];
    // d_in[2]/d_in[3]: segments are contiguous, equal-size L=512 by construction.
    const int E = in_sizes[0];
    const int G = E / L;
    const int nblocks = (G + WPB - 1) / WPB;

    int*    counter  = (int*)d_ws;                       // 4 B, zeroed below
    float4* partials = (float4*)((char*)d_ws + 16);      // nblocks float4s

    hipMemsetAsync(counter, 0, sizeof(int), stream);
    graph_loss_kernel<<<nblocks, BLK, 0, stream>>>(logits, targets, G,
                                                   counter, partials,
                                                   (float*)d_out);
}

// Round 8
// 87.448 us; speedup vs baseline: 1.0785x; 1.0785x over previous
//
#include <hip/hip_runtime.h>
#include <math.h>

#define L        512
#define BLK      256
#define GPB      2          // graphs per block (each graph = LSE wave + pairwise wave)
#define KTOP     32
#define NEGV     (-1e30f)

#define LOG2E    1.4426950408889634f
#define LOG2E10  14.426950408889634f   // (1/T=10) * log2(e)
#define LN2      0.6931471805599453f
#define M_L2E    0.7213475204444817f   // MARGIN(0.5) * log2(e)

#if __has_builtin(__builtin_amdgcn_exp2f)
#define EXP2F(x) __builtin_amdgcn_exp2f(x)
#else
#define EXP2F(x) exp2f(x)
#endif
#if __has_builtin(__builtin_amdgcn_logf)
#define LOG2F(x) __builtin_amdgcn_logf(x)
#else
#define LOG2F(x) __log2f(x)
#endif

// softplus(x)/ln2 with x2 = x*log2e:  max(x2,0) + log2(1 + 2^(-|x2|))
__device__ __forceinline__ float softplus_l2(float x2) {
    return fmaxf(x2, 0.0f) + LOG2F(1.0f + EXP2F(fminf(x2, -x2)));
}

// # of set bits in m strictly below this lane
__device__ __forceinline__ unsigned lanes_below(unsigned long long m) {
    return __builtin_amdgcn_mbcnt_hi((unsigned)(m >> 32),
           __builtin_amdgcn_mbcnt_lo((unsigned)(m & 0xffffffffull), 0u));
}

__global__ __launch_bounds__(BLK) void graph_loss_kernel(
    const float* __restrict__ logits,
    const float* __restrict__ targets,
    int G,
    float* __restrict__ partials /* [gridDim.x*4] */)
{
    __shared__ float pos_s[GPB][L];      // positives, pre-scaled by log2e
    __shared__ float hard_s[GPB][KTOP];  // hard negs in c2 units
    __shared__ float wres[GPB][4];

    const int tid  = threadIdx.x;
    const int lane = tid & 63;
    const int w    = tid >> 6;
    const int role = w >> 1;             // 0 = listwise LSE, 1 = pairwise
    const int slot = w & 1;              // graph slot within block
    const int g    = blockIdx.x * GPB + slot;
    const bool valid = (g < G);          // wave-uniform

    if (valid) {
        // Each lane owns elements [lane*8, lane*8+8): two float4 loads each.
        const float4* lg4 = (const float4*)(logits  + (size_t)g * L);
        const float4* tg4 = (const float4*)(targets + (size_t)g * L);
        const float4 la = lg4[lane * 2], lb = lg4[lane * 2 + 1];
        const float4 ta = tg4[lane * 2], tb = tg4[lane * 2 + 1];
        float v[8]  = {la.x, la.y, la.z, la.w, lb.x, lb.y, lb.z, lb.w};
        float tv[8] = {ta.x, ta.y, ta.z, ta.w, tb.x, tb.y, tb.z, tb.w};
        bool  p[8];
#pragma unroll
        for (int e = 0; e < 8; e++) p[e] = tv[e] > 0.5f;

        if (role == 0) {
            // ================= listwise LSE wave =================
            float u[8];
            float s_mx = NEGV;
            int   pcnt = 0;
#pragma unroll
            for (int e = 0; e < 8; e++) {
                u[e] = v[e] * LOG2E10;
                s_mx = fmaxf(s_mx, u[e]);
                pcnt += p[e] ? 1 : 0;
            }
#pragma unroll
            for (int off = 32; off; off >>= 1)
                s_mx = fmaxf(s_mx, __shfl_xor(s_mx, off, 64));

            float se_all = 0.0f, se_pos = 0.0f;
#pragma unroll
            for (int e = 0; e < 8; e++) {
                const float ep = EXP2F(u[e] - s_mx);
                se_all += ep;
                se_pos += p[e] ? ep : 0.0f;
            }
            float pc = (float)pcnt;
#pragma unroll
            for (int off = 32; off; off >>= 1) {
                se_all += __shfl_xor(se_all, off, 64);
                se_pos += __shfl_xor(se_pos, off, 64);
                pc     += __shfl_xor(pc, off, 64);
            }
            float lw = 0.0f, hp = 0.0f;
            if (pc > 0.0f) {
                hp = 1.0f;
                lw = LN2 * (LOG2F(se_all) - LOG2F(se_pos));
            }
            if (lane == 0) { wres[slot][0] = lw; wres[slot][1] = hp; }
        } else {
            // ================= pairwise top-K wave =================
            unsigned nu[8];  // order-preserving key of negatives; 0 for pos
#pragma unroll
            for (int e = 0; e < 8; e++) {
                const unsigned i = __float_as_uint(v[e]);
                const unsigned msk = (unsigned)((int)i >> 31) | 0x80000000u;
                nu[e] = p[e] ? 0u : (i ^ msk);
            }

            // compact positives (pre-scaled by log2e) into LDS; get P
            int pbase = 0;
#pragma unroll
            for (int e = 0; e < 8; e++) {
                const unsigned long long m = __ballot((int)p[e]);
                if (p[e]) pos_s[slot][pbase + lanes_below(m)] = v[e] * LOG2E;
                pbase += __popcll(m);
            }
            const int P = pbase;
            const int neg_cnt = L - P;
            const int K = neg_cnt < KTOP ? neg_cnt : KTOP;

            float contrib = 0.0f, act = 0.0f;
            if (P > 0 && K > 0) {
                // radix-select threshold key of K-th largest negative
                unsigned prefix = 0u;
                int exact = 0;
                for (int b = 31; b >= 0; --b) {
                    const unsigned cand = prefix | (1u << b);
                    int cnt = 0;
#pragma unroll
                    for (int e = 0; e < 8; e++)
                        cnt += __popcll(__ballot(nu[e] >= cand));
                    if (cnt >= K) {
                        prefix = cand;
                        if (cnt == K) { exact = 1; break; }
                    }
                }
                const unsigned lo = prefix - (unsigned)exact;  // keys > lo
                const unsigned ti = prefix ^ ((prefix & 0x80000000u)
                                              ? 0x80000000u : 0xFFFFFFFFu);
                const float tval = __uint_as_float(ti);
                const float tc2  = fmaf(tval, LOG2E, M_L2E);

                // compact hard negatives in c2 units (0.5 + h)*log2e
                int hbase = 0;
#pragma unroll
                for (int e = 0; e < 8; e++) {
                    const bool gt = nu[e] > lo;
                    const unsigned long long m = __ballot((int)gt);
                    if (gt) hard_s[slot][hbase + lanes_below(m)] =
                                fmaf(v[e], LOG2E, M_L2E);
                    hbase += __popcll(m);
                }
                const int c_gt = hbase;  // ties fill the last K - c_gt slots

                float psum = 0.0f;
                if (K == KTOP) {
                    // lane n<32 holds hard value n; lanes c_gt..31 = tie value
                    const float hc = (lane < c_gt)
                                   ? hard_s[slot][lane & (KTOP - 1)] : tc2;
                    for (int base = 0; base < P; base += 64) {
                        const float qs = pos_s[slot][base + lane];
                        float a0 = 0.0f, a1 = 0.0f, a2 = 0.0f, a3 = 0.0f;
#pragma unroll
                        for (int n = 0; n < KTOP; n += 4) {
                            a0 += softplus_l2(__shfl(hc, n + 0, 64) - qs);
                            a1 += softplus_l2(__shfl(hc, n + 1, 64) - qs);
                            a2 += softplus_l2(__shfl(hc, n + 2, 64) - qs);
                            a3 += softplus_l2(__shfl(hc, n + 3, 64) - qs);
                        }
                        const float s = (a0 + a1) + (a2 + a3);
                        psum += (base + lane < P) ? s : 0.0f;
                    }
                } else {
                    // general path (K < 32): LDS loop + weighted tie term
                    for (int n = 0; n < c_gt; n++) {
                        const float c2 = hard_s[slot][n];
                        for (int pp = lane; pp < P; pp += 64)
                            psum += softplus_l2(c2 - pos_s[slot][pp]);
                    }
                    if (K > c_gt) {
                        float t = 0.0f;
                        for (int pp = lane; pp < P; pp += 64)
                            t += softplus_l2(tc2 - pos_s[slot][pp]);
                        psum += (float)(K - c_gt) * t;
                    }
                }
#pragma unroll
                for (int off = 32; off; off >>= 1)
                    psum += __shfl_xor(psum, off, 64);
                contrib = LN2 * psum / fmaxf((float)P * (float)K, 1.0f);
                act = 1.0f;
            }
            if (lane == 0) { wres[slot][2] = contrib; wres[slot][3] = act; }
        }
    } else if (lane == 0) {
        // keep wres defined for the combine below
        if (role == 0) { wres[slot][0] = 0.0f; wres[slot][1] = 0.0f; }
        else           { wres[slot][2] = 0.0f; wres[slot][3] = 0.0f; }
    }

    __syncthreads();
    if (tid < 4) {
        partials[blockIdx.x * 4 + tid] = wres[0][tid] + wres[1][tid];
    }
}

__global__ __launch_bounds__(256) void finalize_kernel(
    const float* __restrict__ partials, int nblocks, float* __restrict__ out)
{
    float s0 = 0, s1 = 0, s2 = 0, s3 = 0;
    for (int i = threadIdx.x; i < nblocks; i += 256) {
        const float4 p = ((const float4*)partials)[i];
        s0 += p.x; s1 += p.y; s2 += p.z; s3 += p.w;
    }
#pragma unroll
    for (int off = 32; off; off >>= 1) {
        s0 += __shfl_xor(s0, off, 64);
        s1 += __shfl_xor(s1, off, 64);
        s2 += __shfl_xor(s2, off, 64);
        s3 += __shfl_xor(s3, off, 64);
    }
    __shared__ float red[4][4];
    const int lane = threadIdx.x & 63, wid = threadIdx.x >> 6;
    if (lane == 0) { red[wid][0]=s0; red[wid][1]=s1; red[wid][2]=s2; red[wid][3]=s3; }
    __syncthreads();
    if (threadIdx.x == 0) {
        const float a0 = red[0][0]+red[1][0]+red[2][0]+red[3][0];
        const float a1 = red[0][1]+red[1][1]+red[2][1]+red[3][1];
        const float a2 = red[0][2]+red[1][2]+red[2][2]+red[3][2];
        const float a3 = red[0][3]+red[1][3]+red[2][3]+red[3][3];
        const float listwise = a0 / fmaxf(a1, 1.0f);
        const float pairwise = a2 / fmaxf(a3, 1.0f);
        out[0] = 1.0f * listwise + 0.5f * pairwise;
    }
}

extern "C" void kernel_launch(void* const* d_in, const int* in_sizes, int n_in,
                              void* d_out, int out_size, void* d_ws, size_t ws_size,
                              hipStream_t stream) {
    const float* logits  = (const float*)d_in[0];
    const float* targets = (const float*)d_in[1];
    // d_in[2]/d_in[3]: segments are contiguous, equal-size L=512 by construction.
    const int E = in_sizes[0];
    const int G = E / L;
    const int nblocks = (G + GPB - 1) / GPB;

    float* partials = (float*)d_ws;  // nblocks*4 floats, fully overwritten
    graph_loss_kernel<<<nblocks, BLK, 0, stream>>>(logits, targets, G, partials);
    finalize_kernel<<<1, 256, 0, stream>>>(partials, nblocks, (float*)d_out);
}

// Round 9
// 80.783 us; speedup vs baseline: 1.1675x; 1.0825x over previous
//
#include <hip/hip_runtime.h>
#include <math.h>

#define L        512
#define BLK      256
#define WPB      4          // waves (graphs) per block
#define KTOP     32
#define NEGV     (-1e30f)

#define LOG2E    1.4426950408889634f
#define LOG2E10  14.426950408889634f   // (1/T=10) * log2(e)
#define LN2      0.6931471805599453f
#define M_L2E    0.7213475204444817f   // MARGIN(0.5) * log2(e)

#if __has_builtin(__builtin_amdgcn_exp2f)
#define EXP2F(x) __builtin_amdgcn_exp2f(x)
#else
#define EXP2F(x) exp2f(x)
#endif
#if __has_builtin(__builtin_amdgcn_logf)
#define LOG2F(x) __builtin_amdgcn_logf(x)
#else
#define LOG2F(x) __log2f(x)
#endif

// softplus(x)/ln2 with x2 = x*log2e:  max(x2,0) + log2(1 + 2^(-|x2|))
__device__ __forceinline__ float softplus_l2(float x2) {
    return fmaxf(x2, 0.0f) + LOG2F(1.0f + EXP2F(fminf(x2, -x2)));
}

// # of set bits in m strictly below this lane
__device__ __forceinline__ unsigned lanes_below(unsigned long long m) {
    return __builtin_amdgcn_mbcnt_hi((unsigned)(m >> 32),
           __builtin_amdgcn_mbcnt_lo((unsigned)(m & 0xffffffffull), 0u));
}

__global__ __launch_bounds__(BLK) void graph_loss_kernel(
    const float* __restrict__ logits,
    const float* __restrict__ targets,
    int G,
    float* __restrict__ partials /* [gridDim.x*4] */)
{
    __shared__ float pos_s[WPB][L];      // positives, pre-scaled by log2e
    __shared__ float hard_s[WPB][KTOP];  // hard negs in c2 units
    __shared__ float wres[WPB][4];

    const int tid  = threadIdx.x;
    const int lane = tid & 63;
    const int w    = tid >> 6;
    const int g    = blockIdx.x * WPB + w;
    const bool valid = (g < G);          // wave-uniform

    float lw = 0.0f, contrib = 0.0f, hp = 0.0f, act = 0.0f;

    if (valid) {
        // Each lane owns elements [lane*8, lane*8+8): two float4 loads each.
        const float4* lg4 = (const float4*)(logits  + (size_t)g * L);
        const float4* tg4 = (const float4*)(targets + (size_t)g * L);
        const float4 la = lg4[lane * 2], lb = lg4[lane * 2 + 1];
        const float4 ta = tg4[lane * 2], tb = tg4[lane * 2 + 1];
        float v[8]  = {la.x, la.y, la.z, la.w, lb.x, lb.y, lb.z, lb.w};
        float tv[8] = {ta.x, ta.y, ta.z, ta.w, tb.x, tb.y, tb.z, tb.w};
        bool  p[8];
        unsigned nu[8];  // order-preserving uint key of negatives; 0 for pos

#pragma unroll
        for (int e = 0; e < 8; e++) {
            p[e] = tv[e] > 0.5f;
            const unsigned i = __float_as_uint(v[e]);
            const unsigned msk = (unsigned)((int)i >> 31) | 0x80000000u;
            nu[e] = p[e] ? 0u : (i ^ msk);
        }

        // ---- compact positives (pre-scaled by log2e) into LDS; get P ----
        int pbase = 0;
#pragma unroll
        for (int e = 0; e < 8; e++) {
            const unsigned long long m = __ballot((int)p[e]);
            if (p[e]) pos_s[w][pbase + lanes_below(m)] = v[e] * LOG2E;
            pbase += __popcll(m);
        }
        const int P = pbase;

        // ---- listwise LSEs in log2 domain; shared max (s_mx cancels) ----
        float u[8];
        float s_mx = NEGV;
#pragma unroll
        for (int e = 0; e < 8; e++) {
            u[e] = v[e] * LOG2E10;
            s_mx = fmaxf(s_mx, u[e]);
        }
#pragma unroll
        for (int off = 32; off; off >>= 1)
            s_mx = fmaxf(s_mx, __shfl_xor(s_mx, off, 64));

        float se_all = 0.0f, se_pos = 0.0f;
#pragma unroll
        for (int e = 0; e < 8; e++) {
            const float ep = EXP2F(u[e] - s_mx);
            se_all += ep;
            se_pos += p[e] ? ep : 0.0f;
        }
#pragma unroll
        for (int off = 32; off; off >>= 1) {
            se_all += __shfl_xor(se_all, off, 64);
            se_pos += __shfl_xor(se_pos, off, 64);
        }

        if (P > 0) {
            hp = 1.0f;
            lw = LN2 * (LOG2F(se_all) - LOG2F(se_pos));
        }
        const int neg_cnt = L - P;
        const int K = neg_cnt < KTOP ? neg_cnt : KTOP;

        if (P > 0 && K > 0) {
            // ---- radix-select threshold key of K-th largest negative ----
            unsigned prefix = 0u;
            int exact = 0;
            for (int b = 31; b >= 0; --b) {
                const unsigned cand = prefix | (1u << b);
                int cnt = 0;
#pragma unroll
                for (int e = 0; e < 8; e++)
                    cnt += __popcll(__ballot(nu[e] >= cand));
                if (cnt >= K) {
                    prefix = cand;
                    if (cnt == K) { exact = 1; break; }
                }
            }
            const unsigned lo = prefix - (unsigned)exact;  // select keys > lo
            const unsigned ti = prefix ^ ((prefix & 0x80000000u) ? 0x80000000u
                                                                 : 0xFFFFFFFFu);
            const float tval = __uint_as_float(ti);
            const float tc2  = fmaf(tval, LOG2E, M_L2E);   // tie value, c2 units

            // ---- compact hard negatives in c2 units (0.5 + h)*log2e ----
            int hbase = 0;
#pragma unroll
            for (int e = 0; e < 8; e++) {
                const bool gt = nu[e] > lo;
                const unsigned long long m = __ballot((int)gt);
                if (gt) hard_s[w][hbase + lanes_below(m)] =
                            fmaf(v[e], LOG2E, M_L2E);
                hbase += __popcll(m);
            }
            const int c_gt = hbase;  // ties fill the remaining K - c_gt slots

            float psum = 0.0f;
            if (K == KTOP) {
                // fast path: lane n<32 holds hard value n in a register;
                // lanes c_gt..31 hold the tie value (exact top-32 multiset).
                const float hc = (lane < c_gt) ? hard_s[w][lane & (KTOP - 1)]
                                               : tc2;
                for (int base = 0; base < P; base += 64) {
                    const float qs = pos_s[w][base + lane]; // garbage if >=P,
                    float a0 = 0.0f, a1 = 0.0f, a2 = 0.0f, a3 = 0.0f;
#pragma unroll
                    for (int n = 0; n < KTOP; n += 4) {     // masked out below
                        a0 += softplus_l2(__shfl(hc, n + 0, 64) - qs);
                        a1 += softplus_l2(__shfl(hc, n + 1, 64) - qs);
                        a2 += softplus_l2(__shfl(hc, n + 2, 64) - qs);
                        a3 += softplus_l2(__shfl(hc, n + 3, 64) - qs);
                    }
                    const float s = (a0 + a1) + (a2 + a3);
                    psum += (base + lane < P) ? s : 0.0f;
                }
            } else {
                // general path (K < 32): LDS loop + weighted tie term
                for (int n = 0; n < c_gt; n++) {
                    const float c2 = hard_s[w][n];
                    for (int pp = lane; pp < P; pp += 64)
                        psum += softplus_l2(c2 - pos_s[w][pp]);
                }
                if (K > c_gt) {
                    float t = 0.0f;
                    for (int pp = lane; pp < P; pp += 64)
                        t += softplus_l2(tc2 - pos_s[w][pp]);
                    psum += (float)(K - c_gt) * t;
                }
            }
#pragma unroll
            for (int off = 32; off; off >>= 1)
                psum += __shfl_xor(psum, off, 64);
            contrib = LN2 * psum / fmaxf((float)P * (float)K, 1.0f);
            act = 1.0f;
        }
    }

    if (lane == 0) {
        wres[w][0] = lw;
        wres[w][1] = hp;
        wres[w][2] = contrib;
        wres[w][3] = act;
    }
    __syncthreads();
    if (tid < 4) {
        partials[blockIdx.x * 4 + tid] =
            wres[0][tid] + wres[1][tid] + wres[2][tid] + wres[3][tid];
    }
}

__global__ __launch_bounds__(256) void finalize_kernel(
    const float* __restrict__ partials, int nblocks, float* __restrict__ out)
{
    float s0 = 0, s1 = 0, s2 = 0, s3 = 0;
    for (int i = threadIdx.x; i < nblocks; i += 256) {
        const float4 p = ((const float4*)partials)[i];
        s0 += p.x; s1 += p.y; s2 += p.z; s3 += p.w;
    }
#pragma unroll
    for (int off = 32; off; off >>= 1) {
        s0 += __shfl_xor(s0, off, 64);
        s1 += __shfl_xor(s1, off, 64);
        s2 += __shfl_xor(s2, off, 64);
        s3 += __shfl_xor(s3, off, 64);
    }
    __shared__ float red[4][4];
    const int lane = threadIdx.x & 63, wid = threadIdx.x >> 6;
    if (lane == 0) { red[wid][0]=s0; red[wid][1]=s1; red[wid][2]=s2; red[wid][3]=s3; }
    __syncthreads();
    if (threadIdx.x == 0) {
        const float a0 = red[0][0]+red[1][0]+red[2][0]+red[3][0];
        const float a1 = red[0][1]+red[1][1]+red[2][1]+red[3][1];
        const float a2 = red[0][2]+red[1][2]+red[2][2]+red[3][2];
        const float a3 = red[0][3]+red[1][3]+red[2][3]+red[3][3];
        const float listwise = a0 / fmaxf(a1, 1.0f);
        const float pairwise = a2 / fmaxf(a3, 1.0f);
        out[0] = 1.0f * listwise + 0.5f * pairwise;
    }
}

extern "C" void kernel_launch(void* const* d_in, const int* in_sizes, int n_in,
                              void* d_out, int out_size, void* d_ws, size_t ws_size,
                              hipStream_t stream) {
    const float* logits  = (const float*)d_in[0];
    const float* targets = (const float*)d_in[1];
    // d_in[2]/d_in[3]: segments are contiguous, equal-size L=512 by construction.
    const int E = in_sizes[0];
    const int G = E / L;
    const int nblocks = (G + WPB - 1) / WPB;

    float* partials = (float*)d_ws;  // nblocks*4 floats, fully overwritten
    graph_loss_kernel<<<nblocks, BLK, 0, stream>>>(logits, targets, G, partials);
    finalize_kernel<<<1, 256, 0, stream>>>(partials, nblocks, (float*)d_out);
}